// Round 8
// baseline (3466.156 us; speedup 1.0000x reference)
//
#include <hip/hip_runtime.h>
#include <hip/hip_fp16.h>

// GCN 2-layer — ONE persistent mega-kernel, R8: deadlock-free monotonic sync.
// R7 hung: gen broadcast used STORES to 64 lines; releasers of consecutive
// barriers can interleave, an old store can overwrite a newer target on a
// line -> pollers wait forever. R8 barrier: EVERY counter is monotonic,
// arrival groups (32 padded lines, fetch_add; last = reads gsz*target-1),
// master (last group reads 32*target-1), release = fetch_add(+1) on 64
// padded gen lines (adds commute -> interleaving harmless), poll own line
// for >= target with s_sleep backoff. No resets anywhere.
// Claims: 8 partitioned padded counters (blockIdx&7); F chunk=1 tile
// (6250 claims, ~3/block), G chunk=2 groups (12500 claims, ~6/block).
// Phases: A hist||wt -> B scanT -> C localscan+scatter -> D fillb+y ->
//         F fused gather+GEMM1+GEMM2 -> G layer-2 gather -> out. 5 gsyncs.

constexpr int NN = 100000;
constexpr int NE = 1600000;
constexpr int BSH = 7;
constexpr int NB = (NN + 127) >> BSH;   // 782
constexpr int NBLK = 256;
constexpr int EPB = NE / NBLK;          // 6250
constexpr int TSTR = 784;
constexpr int NTILE = NN / 16;          // 6250
constexpr int NG4 = NN / 4;             // 25000
constexpr int TPP = 782;                // F tiles per partition (8*782>=6250)
constexpr int GCL = NG4 / 2;            // 12500 G claims (2 groups each)
constexpr int CPP = 1563;               // G claims per partition (8*1563>=12500)

// ctl layout (ints; every slot on its own 64B line)
constexpr int C_MASTER = 0;
constexpr int C_GRP = 16;     // 32 slots: 16 + g*16
constexpr int C_GEN = 528;    // 64 slots: 528 + L*16
constexpr int C_CLF = 1552;   // 8 slots: 1552 + p*16
constexpr int C_CLG = 1680;   // 8 slots: 1680 + p*16
constexpr int C_INTS = 1808;

typedef _Float16 f16x8 __attribute__((ext_vector_type(8)));
typedef float f32x4 __attribute__((ext_vector_type(4)));

// ---- monotonic hierarchical device barrier (all blocks co-resident) ----
__device__ __forceinline__ void gsync(int* ctl, int target) {
  __syncthreads();
  if (threadIdx.x == 0) {
    __threadfence();  // agent-scope visibility of this block's phase writes
    const int g = blockIdx.x & 31;
    const int gsz = (int)gridDim.x >> 5;  // gridDim % 32 == 0 by construction
    int a = __hip_atomic_fetch_add(&ctl[C_GRP + g * 16], 1, __ATOMIC_ACQ_REL,
                                   __HIP_MEMORY_SCOPE_AGENT);
    if (a == gsz * target - 1) {
      int m = __hip_atomic_fetch_add(&ctl[C_MASTER], 1, __ATOMIC_ACQ_REL,
                                     __HIP_MEMORY_SCOPE_AGENT);
      if (m == 32 * target - 1) {
        for (int L = 0; L < 64; ++L)
          __hip_atomic_fetch_add(&ctl[C_GEN + L * 16], 1, __ATOMIC_ACQ_REL,
                                 __HIP_MEMORY_SCOPE_AGENT);
      }
    }
    const int line = C_GEN + (blockIdx.x & 63) * 16;
    while (__hip_atomic_load(&ctl[line], __ATOMIC_ACQUIRE,
                             __HIP_MEMORY_SCOPE_AGENT) < target)
      __builtin_amdgcn_s_sleep(16);
  }
  __syncthreads();
}

__global__ __launch_bounds__(256, 8) void k_mega(
    const float4* __restrict__ x4, const int* __restrict__ rows,
    const int* __restrict__ cols, const float* __restrict__ W1,
    const float* __restrict__ b1, const float* __restrict__ W2,
    const float* __restrict__ b2, float* __restrict__ out,
    int* __restrict__ table, int* __restrict__ startOff,
    int* __restrict__ btot, int* __restrict__ bucketBase,
    unsigned* __restrict__ binned, int* __restrict__ rowptr,
    int* __restrict__ deg, float* __restrict__ dinv,
    int* __restrict__ srcIdx, __half* __restrict__ Wt1,
    __half* __restrict__ Wt2, __half* __restrict__ y,
    __half* __restrict__ z, int* ctl) {
  __shared__ __align__(16) char smem[8704];
  __shared__ int sclaim;
  const int tid = threadIdx.x;
  const int nb_ = gridDim.x;
  int gen = 0;

  // ============ phase A: histogram (vb<NBLK) + weight transpose ============
  for (int vb = blockIdx.x; vb < NBLK + 96; vb += nb_) {
    if (vb < NBLK) {
      int* cnt = (int*)smem;
      for (int i = tid; i < NB; i += 256) cnt[i] = 0;
      __syncthreads();
      int base = vb * EPB;
      for (int i = tid; i < EPB; i += 256)
        atomicAdd(&cnt[cols[base + i] >> BSH], 1);
      __syncthreads();
      for (int i = tid; i < NB; i += 256) table[vb * TSTR + i] = cnt[i];
      __syncthreads();
    } else {
      int i = (vb - NBLK) * 256 + tid;  // 24576 = 16384 + 8192
      if (i < 16384) {
        int k = i >> 7, n = i & 127;
        Wt1[n * 128 + k] = __float2half(W1[i]);
      } else {
        int j = i - 16384;
        int k = j >> 6, n = j & 63;
        Wt2[n * 128 + k] = __float2half(W2[j]);
      }
    }
  }
  gsync(ctl, ++gen);

  // ============ phase B: scan table columns -> startOff, btot ============
  for (int vb = blockIdx.x; vb < NB; vb += nb_) {
    int* s = (int*)smem;
    int v = table[tid * TSTR + vb];
    s[tid] = v;
    __syncthreads();
    for (int off = 1; off < 256; off <<= 1) {
      int tmp = (tid >= off) ? s[tid - off] : 0;
      __syncthreads();
      s[tid] += tmp;
      __syncthreads();
    }
    startOff[tid * TSTR + vb] = s[tid] - v;
    if (tid == 255) btot[vb] = s[tid];
    __syncthreads();
  }
  gsync(ctl, ++gen);

  // ===== phase C: block-local scan of btot -> bb; scatter edges =====
  if (blockIdx.x < NBLK) {
    int* bb = (int*)smem;             // NB ints
    int* s = (int*)(smem + 3200);     // 256 ints
    int* scnt = (int*)(smem + 4352);  // NB ints
    int base4 = tid * 4;
    int d0 = (base4 + 0 < NB) ? btot[base4 + 0] : 0;
    int d1 = (base4 + 1 < NB) ? btot[base4 + 1] : 0;
    int d2 = (base4 + 2 < NB) ? btot[base4 + 2] : 0;
    int d3 = (base4 + 3 < NB) ? btot[base4 + 3] : 0;
    int tsum = d0 + d1 + d2 + d3;
    s[tid] = tsum;
    __syncthreads();
    for (int off = 1; off < 256; off <<= 1) {
      int tmp = (tid >= off) ? s[tid - off] : 0;
      __syncthreads();
      s[tid] += tmp;
      __syncthreads();
    }
    int ex = s[tid] - tsum;
    if (base4 + 0 < NB) bb[base4 + 0] = ex;
    if (base4 + 1 < NB) bb[base4 + 1] = ex + d0;
    if (base4 + 2 < NB) bb[base4 + 2] = ex + d0 + d1;
    if (base4 + 3 < NB) bb[base4 + 3] = ex + d0 + d1 + d2;
    __syncthreads();
    if (blockIdx.x == 0)
      for (int i = tid; i < NB; i += 256) bucketBase[i] = bb[i];
    for (int i = tid; i < NB; i += 256)
      scnt[i] = bb[i] + startOff[blockIdx.x * TSTR + i];
    __syncthreads();
    int base = blockIdx.x * EPB;
    for (int i = tid; i < EPB; i += 256) {
      int c = cols[base + i];
      int r = rows[base + i];
      int pos = atomicAdd(&scnt[c >> BSH], 1);
      binned[pos] = ((unsigned)r << BSH) | (unsigned)(c & 127);
    }
  }
  gsync(ctl, ++gen);

  // ===== phase D: per-bucket fill: deg/rowptr/dinv + srcIdx + y =====
  for (int vb = blockIdx.x; vb < NB; vb += nb_) {
    int* cnt = (int*)smem;            // 128 ints
    int* sc = cnt + 128;              // 128 ints
    int* rp = sc + 128;               // 128 ints
    float* sdv = (float*)(rp + 128);  // 128 floats
    int nb0 = vb << BSH;
    int nn = min(128, NN - nb0);
    if (tid < 128) cnt[tid] = 0;
    __syncthreads();
    int ebeg = bucketBase[vb];
    int eend = ebeg + btot[vb];
    for (int p = ebeg + tid; p < eend; p += 256)
      atomicAdd(&cnt[binned[p] & 127], 1);
    __syncthreads();
    int v = (tid < 128) ? cnt[tid] : 0;
    if (tid < 128) sc[tid] = v;
    __syncthreads();
    for (int off = 1; off < 128; off <<= 1) {
      int tmp = (tid < 128 && tid >= off) ? sc[tid - off] : 0;
      __syncthreads();
      if (tid < 128) sc[tid] += tmp;
      __syncthreads();
    }
    if (tid < 128) {
      int ex = sc[tid] - v;
      rp[tid] = ebeg + ex;
      float dv = rsqrtf((float)v + 1.0f);
      sdv[tid] = dv;
      if (tid < nn) {
        rowptr[nb0 + tid] = ebeg + ex;
        deg[nb0 + tid] = v;
        dinv[nb0 + tid] = dv;
      }
      cnt[tid] = 0;
    }
    __syncthreads();
    for (int p = ebeg + tid; p < eend; p += 256) {
      unsigned pk = binned[p];
      int cl = pk & 127;
      int lo = atomicAdd(&cnt[cl], 1);
      srcIdx[rp[cl] + lo] = (int)(pk >> BSH);
    }
    // fused k_y for this bucket's rows
    int tot = nn << 5;  // nn rows * 32 float4
    const float4* xb = x4 + ((size_t)nb0 << 5);
    float2* yb = (float2*)y + ((size_t)nb0 << 5);
    for (int i = tid; i < tot; i += 256) {
      float sfac = sdv[i >> 5];
      float4 vv = xb[i];
      union { __half2 h[2]; float2 f; } u;
      u.h[0] = __floats2half2_rn(vv.x * sfac, vv.y * sfac);
      u.h[1] = __floats2half2_rn(vv.z * sfac, vv.w * sfac);
      yb[i] = u.f;
    }
    __syncthreads();
  }
  gsync(ctl, ++gen);

  // ===== phase F: fused gather + GEMM1 + GEMM2; partitioned 1-tile claims ==
  {
    __half(*sA)[136] = (__half(*)[136])smem;
    __half(*sB)[136] = (__half(*)[136])(smem + 4352);
    const int w = tid >> 6, l = tid & 63;
    const int quad = l >> 4, m = l & 15;
    const int part = blockIdx.x & 7;
    const int cbase = part * TPP;
    const int cend = (cbase + TPP < NTILE) ? cbase + TPP : NTILE;
    for (;;) {
      if (tid == 0)
        sclaim = cbase + __hip_atomic_fetch_add(&ctl[C_CLF + part * 16], 1,
                                                __ATOMIC_RELAXED,
                                                __HIP_MEMORY_SCOPE_AGENT);
      __syncthreads();
      const int tile = sclaim;
      if (tile >= cend) break;
      const int blk0 = tile * 16;
      // ---- gather: wave w -> rows [w*4, w*4+4), wave-uniform per node ----
      for (int i = 0; i < 4; ++i) {
        const int lr = w * 4 + i;
        const int node = blk0 + lr;
        const int d = deg[node];
        const int ptr = rowptr[node];
        float acc[8];
#pragma unroll
        for (int j = 0; j < 8; j++) acc[j] = 0.0f;
        for (int base = 0; base < d; base += 64) {
          int cntv = min(64, d - base);
          int my = (l < cntv) ? srcIdx[ptr + base + l] : 0;
          int k = 0;
          for (; k + 16 <= cntv; k += 16) {  // 4 loads (4KB) in flight
            int s0 = __shfl(my, k + quad);
            int s1 = __shfl(my, k + 4 + quad);
            int s2 = __shfl(my, k + 8 + quad);
            int s3 = __shfl(my, k + 12 + quad);
            f16x8 v0 = *(const f16x8*)(y + (size_t)s0 * 128 + m * 8);
            f16x8 v1 = *(const f16x8*)(y + (size_t)s1 * 128 + m * 8);
            f16x8 v2 = *(const f16x8*)(y + (size_t)s2 * 128 + m * 8);
            f16x8 v3 = *(const f16x8*)(y + (size_t)s3 * 128 + m * 8);
#pragma unroll
            for (int j = 0; j < 8; j++) acc[j] += (float)v0[j];
#pragma unroll
            for (int j = 0; j < 8; j++) acc[j] += (float)v1[j];
#pragma unroll
            for (int j = 0; j < 8; j++) acc[j] += (float)v2[j];
#pragma unroll
            for (int j = 0; j < 8; j++) acc[j] += (float)v3[j];
          }
          for (; k + 8 <= cntv; k += 8) {
            int s0 = __shfl(my, k + quad);
            int s1 = __shfl(my, k + 4 + quad);
            f16x8 v0 = *(const f16x8*)(y + (size_t)s0 * 128 + m * 8);
            f16x8 v1 = *(const f16x8*)(y + (size_t)s1 * 128 + m * 8);
#pragma unroll
            for (int j = 0; j < 8; j++) acc[j] += (float)v0[j];
#pragma unroll
            for (int j = 0; j < 8; j++) acc[j] += (float)v1[j];
          }
          for (; k < cntv; k += 4) {  // remainder, predicated
            int idx = k + quad;
            bool valid = idx < cntv;
            int s0 = __shfl(my, valid ? idx : 0);
            f16x8 v0 = *(const f16x8*)(y + (size_t)s0 * 128 + m * 8);
            if (valid) {
#pragma unroll
              for (int j = 0; j < 8; j++) acc[j] += (float)v0[j];
            }
          }
        }
#pragma unroll
        for (int j = 0; j < 8; j++) acc[j] += __shfl_xor(acc[j], 16);
#pragma unroll
        for (int j = 0; j < 8; j++) acc[j] += __shfl_xor(acc[j], 32);
        if (quad == 0) {
          f16x8 sv = *(const f16x8*)(y + (size_t)node * 128 + m * 8);
          float scn = dinv[node];
          f16x8 o;
#pragma unroll
          for (int j = 0; j < 8; j++)
            o[j] = (_Float16)((acc[j] + (float)sv[j]) * scn);
          *(f16x8*)(&sA[lr][m * 8]) = o;
        }
      }
      __syncthreads();
      // ---- GEMM1: h1 = relu(aggX @ W1 + b1); wave w -> cols 2w,2w+1 ----
      f16x8 afrag[4];
#pragma unroll
      for (int kk = 0; kk < 4; kk++)
        afrag[kk] = *(const f16x8*)(&sA[m][kk * 32 + quad * 8]);
      f32x4 acc1[2];
#pragma unroll
      for (int t = 0; t < 2; t++) {
        float bv = b1[(w * 2 + t) * 16 + m];
        acc1[t] = (f32x4){bv, bv, bv, bv};
      }
#pragma unroll
      for (int kk = 0; kk < 4; kk++) {
#pragma unroll
        for (int t = 0; t < 2; t++) {
          f16x8 b = *(const f16x8*)(Wt1 + (size_t)((w * 2 + t) * 16 + m) * 128 +
                                    kk * 32 + quad * 8);
          acc1[t] = __builtin_amdgcn_mfma_f32_16x16x32_f16(afrag[kk], b,
                                                           acc1[t], 0, 0, 0);
        }
      }
#pragma unroll
      for (int t = 0; t < 2; t++)
#pragma unroll
        for (int i = 0; i < 4; i++)
          sB[quad * 4 + i][(w * 2 + t) * 16 + m] =
              __float2half(fmaxf(acc1[t][i], 0.0f));
      __syncthreads();
      // ---- GEMM2: z = (h1 @ W2) * dinv; wave w -> col tile w ----
      f16x8 hfrag[4];
#pragma unroll
      for (int kk = 0; kk < 4; kk++)
        hfrag[kk] = *(const f16x8*)(&sB[m][kk * 32 + quad * 8]);
      f32x4 acc2 = (f32x4){0.f, 0.f, 0.f, 0.f};
#pragma unroll
      for (int kk = 0; kk < 4; kk++) {
        f16x8 b = *(const f16x8*)(Wt2 + (size_t)(w * 16 + m) * 128 + kk * 32 +
                                  quad * 8);
        acc2 = __builtin_amdgcn_mfma_f32_16x16x32_f16(hfrag[kk], b, acc2, 0, 0, 0);
      }
      float rs[4];
#pragma unroll
      for (int i = 0; i < 4; i++) rs[i] = dinv[blk0 + quad * 4 + i];
#pragma unroll
      for (int i = 0; i < 4; i++)
        sA[quad * 4 + i][w * 16 + m] = __float2half(acc2[i] * rs[i]);
      __syncthreads();
      // ---- store 16x64 halves ----
      if (tid < 128) {
        int r = tid >> 3, cc = tid & 7;
        *(float4*)(z + (size_t)(blk0 + r) * 64 + cc * 8) =
            *(const float4*)(&sA[r][cc * 8]);
      }
      __syncthreads();  // protect sA/sclaim before next claim
    }
  }
  gsync(ctl, ++gen);

  // ===== phase G: layer-2 gather -> out; partitioned 2-group claims =====
  {
    const int lane = tid & 63;
    const int g = lane >> 3;
    const int c = lane & 7;
    const size_t coff = (size_t)c * 8;
    const int part = blockIdx.x & 7;
    const int cbase = part * CPP;
    const int cend = (cbase + CPP < GCL) ? cbase + CPP : GCL;
    for (;;) {
      if (tid == 0)
        sclaim = cbase + __hip_atomic_fetch_add(&ctl[C_CLG + part * 16], 1,
                                                __ATOMIC_RELAXED,
                                                __HIP_MEMORY_SCOPE_AGENT);
      __syncthreads();
      const int cl0 = sclaim;
      if (cl0 >= cend) break;
      for (int gg = cl0 * 2; gg < cl0 * 2 + 2; ++gg) {
        int node = gg * 4 + (tid >> 6);
        int d = deg[node];
        int p = rowptr[node];
        float acc[8];
#pragma unroll
        for (int i = 0; i < 8; i++) acc[i] = 0.0f;
        for (int base = 0; base < d; base += 64) {
          int cnt = min(64, d - base);
          int my = (lane < cnt) ? srcIdx[p + base + lane] : 0;
          int k = 0;
          for (; k + 16 <= cnt; k += 16) {
            int s0 = __shfl(my, k + g);
            int s1 = __shfl(my, k + 8 + g);
            f16x8 v0 = *(const f16x8*)(z + (size_t)s0 * 64 + coff);
            f16x8 v1 = *(const f16x8*)(z + (size_t)s1 * 64 + coff);
#pragma unroll
            for (int i = 0; i < 8; i++) acc[i] += (float)v0[i];
#pragma unroll
            for (int i = 0; i < 8; i++) acc[i] += (float)v1[i];
          }
          for (; k < cnt; k += 8) {
            int idx = k + g;
            bool valid = idx < cnt;
            int s0 = __shfl(my, valid ? idx : 0);
            f16x8 v0 = *(const f16x8*)(z + (size_t)s0 * 64 + coff);
            if (valid) {
#pragma unroll
              for (int i = 0; i < 8; i++) acc[i] += (float)v0[i];
            }
          }
        }
#pragma unroll
        for (int i = 0; i < 8; i++) acc[i] += __shfl_xor(acc[i], 8);
#pragma unroll
        for (int i = 0; i < 8; i++) acc[i] += __shfl_xor(acc[i], 16);
#pragma unroll
        for (int i = 0; i < 8; i++) acc[i] += __shfl_xor(acc[i], 32);
        if (g == 0) {
          f16x8 sv = *(const f16x8*)(z + (size_t)node * 64 + coff);
          float s = dinv[node];
          const float4* b4 = (const float4*)b2;
          float4 bv0 = b4[2 * c], bv1 = b4[2 * c + 1];
          float4 o0, o1;
          o0.x = (acc[0] + (float)sv[0]) * s + bv0.x;
          o0.y = (acc[1] + (float)sv[1]) * s + bv0.y;
          o0.z = (acc[2] + (float)sv[2]) * s + bv0.z;
          o0.w = (acc[3] + (float)sv[3]) * s + bv0.w;
          o1.x = (acc[4] + (float)sv[4]) * s + bv1.x;
          o1.y = (acc[5] + (float)sv[5]) * s + bv1.y;
          o1.z = (acc[6] + (float)sv[6]) * s + bv1.z;
          o1.w = (acc[7] + (float)sv[7]) * s + bv1.w;
          float4* op = (float4*)(out + (size_t)node * 64 + coff);
          op[0] = o0;
          op[1] = o1;
        }
      }
      __syncthreads();  // protect sclaim
    }
  }
}

extern "C" void kernel_launch(void* const* d_in, const int* in_sizes, int n_in,
                              void* d_out, int out_size, void* d_ws, size_t ws_size,
                              hipStream_t stream) {
  const float* x = (const float*)d_in[0];
  const int* ei = (const int*)d_in[1];
  const int* rows = ei;
  const int* cols = ei + NE;
  const float* W1 = (const float*)d_in[3];
  const float* b1 = (const float*)d_in[4];
  const float* W2 = (const float*)d_in[5];
  const float* b2 = (const float*)d_in[6];
  float* out = (float*)d_out;

  char* base = (char*)d_ws;
  constexpr size_t MB = 1 << 20;
  int* deg = (int*)(base + 0 * MB);
  int* rowptr = (int*)(base + 1 * MB);
  float* dinv = (float*)(base + 2 * MB);
  int* btot = (int*)(base + 3 * MB);
  int* bucketBase = (int*)(base + 3 * MB + 16 * 1024);
  __half* Wt1 = (__half*)(base + 3 * MB + 64 * 1024);
  __half* Wt2 = (__half*)(base + 3 * MB + 128 * 1024);
  int* ctl = (int*)(base + 3 * MB + 512 * 1024);  // 7.3 KB control block
  int* table = (int*)(base + 4 * MB);
  int* startOff = (int*)(base + 5 * MB);
  unsigned* binned = (unsigned*)(base + 6 * MB);
  int* srcIdx = (int*)(base + 13 * MB);
  __half* y = (__half*)(base + 20 * MB);
  __half* z = (__half*)(base + 46 * MB);

  hipMemsetAsync(ctl, 0, C_INTS * sizeof(int), stream);

  static int nblk = 0;
  if (nblk == 0) {
    int b = 0;
    if (hipOccupancyMaxActiveBlocksPerMultiprocessor(&b, k_mega, 256, 0) !=
            hipSuccess ||
        b < 1)
      b = 4;
    if (b > 8) b = 8;
    nblk = b * 256;  // multiple of 256 -> divisible by 32 (gsync requires)
  }

  k_mega<<<nblk, 256, 0, stream>>>(
      (const float4*)x, rows, cols, W1, b1, W2, b2, out, table, startOff, btot,
      bucketBase, binned, rowptr, deg, dinv, srcIdx, Wt1, Wt2, y, z, ctl);
}

// Round 9
// 294.461 us; speedup vs baseline: 11.7712x; 11.7712x over previous
//
#include <hip/hip_runtime.h>
#include <hip/hip_fp16.h>

// GCN 2-layer, CSR-gather, fp16 storage / fp32 math, MFMA GEMMs. R9.
// R6-R8 lesson (persistent mega-kernel ABANDONED): software grid barriers on
// MI355X are structurally bad — agent-scope polls read stale per-XCD L2
// copies (~1.3ms/barrier, R8), system-scope polls burn fabric (R6). Banked
// conclusion: stay multi-kernel; attack dispatch count instead.
// R9 = R4/R5 multi-kernel with two merges (-2 dispatches):
//   k_histwt : edge histogram (256 blks) || weight transpose (96 blks)
//   k_scanT  : column scan of per-block histograms -> startOff, btot
//   k_scatB  : per-block LDS scan of btot (redundant, R6-proven) + scatter
//              edges into bucket-grouped array; block 0 publishes bucketBase
//   k_fillb  : per-bucket deg/rowptr/dinv + node-grouped srcIdx + y=half(x*dinv)
//   k_fused  : gather + GEMM1(relu,b1) + GEMM2(*dinv) per 16-row tile
//              (R5 dispatch-measured 90.0us, occ 72%)
//   k_gath2  : layer-2 gather -> out (+4-deep MLP this round)
// 6 dispatches, no global atomics, no device barriers.

constexpr int NN = 100000;
constexpr int NE = 1600000;
constexpr int BSH = 7;
constexpr int NB = (NN + 127) >> BSH;   // 782
constexpr int NBLK = 256;
constexpr int EPB = NE / NBLK;          // 6250
constexpr int TSTR = 784;

typedef _Float16 f16x8 __attribute__((ext_vector_type(8)));
typedef float f32x4 __attribute__((ext_vector_type(4)));

// ---- histogram (blocks 0..255) + weight transpose (blocks 256..351) ----
__global__ __launch_bounds__(256) void k_histwt(const int* __restrict__ cols,
                                                int* __restrict__ table,
                                                const float* __restrict__ W1,
                                                const float* __restrict__ W2,
                                                __half* __restrict__ Wt1,
                                                __half* __restrict__ Wt2) {
  if (blockIdx.x < NBLK) {
    __shared__ int cnt[NB];
    for (int i = threadIdx.x; i < NB; i += 256) cnt[i] = 0;
    __syncthreads();
    int base = blockIdx.x * EPB;
    for (int i = threadIdx.x; i < EPB; i += 256)
      atomicAdd(&cnt[cols[base + i] >> BSH], 1);
    __syncthreads();
    for (int i = threadIdx.x; i < NB; i += 256)
      table[blockIdx.x * TSTR + i] = cnt[i];
  } else {
    int i = (blockIdx.x - NBLK) * 256 + threadIdx.x;  // 24576 = 16384 + 8192
    if (i < 16384) {
      int k = i >> 7, n = i & 127;
      Wt1[n * 128 + k] = __float2half(W1[i]);
    } else {
      int j = i - 16384;
      int k = j >> 6, n = j & 63;
      Wt2[n * 128 + k] = __float2half(W2[j]);
    }
  }
}

// ------- scan table columns over blocks: startOff + bucket totals ------------
__global__ __launch_bounds__(256) void k_scanT(const int* __restrict__ table,
                                               int* __restrict__ startOff,
                                               int* __restrict__ btot) {
  __shared__ int s[256];
  int b = blockIdx.x, t = threadIdx.x;
  int v = table[t * TSTR + b];
  s[t] = v;
  __syncthreads();
  for (int off = 1; off < 256; off <<= 1) {
    int tmp = (t >= off) ? s[t - off] : 0;
    __syncthreads();
    s[t] += tmp;
    __syncthreads();
  }
  startOff[t * TSTR + b] = s[t] - v;
  if (t == 255) btot[b] = s[t];
}

// ---- per-block LDS scan of btot (redundant across blocks, R6-proven) + -----
// ---- scatter edges into bucket-grouped array; block 0 publishes bases  -----
__global__ __launch_bounds__(256) void k_scatB(const int* __restrict__ rows,
                                               const int* __restrict__ cols,
                                               const int* __restrict__ startOff,
                                               const int* __restrict__ btot,
                                               int* __restrict__ bucketBase,
                                               unsigned* __restrict__ binned) {
  __shared__ int bb[NB];
  __shared__ int s[256];
  __shared__ int scnt[NB];
  int tid = threadIdx.x;
  int base4 = tid * 4;
  int d0 = (base4 + 0 < NB) ? btot[base4 + 0] : 0;
  int d1 = (base4 + 1 < NB) ? btot[base4 + 1] : 0;
  int d2 = (base4 + 2 < NB) ? btot[base4 + 2] : 0;
  int d3 = (base4 + 3 < NB) ? btot[base4 + 3] : 0;
  int tsum = d0 + d1 + d2 + d3;
  s[tid] = tsum;
  __syncthreads();
  for (int off = 1; off < 256; off <<= 1) {
    int tmp = (tid >= off) ? s[tid - off] : 0;
    __syncthreads();
    s[tid] += tmp;
    __syncthreads();
  }
  int ex = s[tid] - tsum;
  if (base4 + 0 < NB) bb[base4 + 0] = ex;
  if (base4 + 1 < NB) bb[base4 + 1] = ex + d0;
  if (base4 + 2 < NB) bb[base4 + 2] = ex + d0 + d1;
  if (base4 + 3 < NB) bb[base4 + 3] = ex + d0 + d1 + d2;
  __syncthreads();
  if (blockIdx.x == 0)  // publish for k_fillb
    for (int i = tid; i < NB; i += 256) bucketBase[i] = bb[i];
  for (int i = tid; i < NB; i += 256)
    scnt[i] = bb[i] + startOff[blockIdx.x * TSTR + i];
  __syncthreads();
  int base = blockIdx.x * EPB;
  for (int i = tid; i < EPB; i += 256) {
    int c = cols[base + i];
    int r = rows[base + i];
    int pos = atomicAdd(&scnt[c >> BSH], 1);
    binned[pos] = ((unsigned)r << BSH) | (unsigned)(c & 127);
  }
}

// ------- per-bucket fill: deg/rowptr/dinv + node-grouped srcIdx + y ----------
__global__ __launch_bounds__(256) void k_fillb(const unsigned* __restrict__ binned,
                                               const int* __restrict__ bucketBase,
                                               const int* __restrict__ btot,
                                               int* __restrict__ rowptr,
                                               int* __restrict__ deg,
                                               float* __restrict__ dinv,
                                               int* __restrict__ srcIdx,
                                               const float4* __restrict__ x4,
                                               float2* __restrict__ y8) {
  __shared__ int cnt[128];
  __shared__ int sc[128];
  __shared__ int rp[128];
  __shared__ float sdv[128];
  int b = blockIdx.x;
  int nb0 = b << BSH;
  int nn = min(128, NN - nb0);
  int tid = threadIdx.x;
  if (tid < 128) cnt[tid] = 0;
  __syncthreads();
  int ebeg = bucketBase[b];
  int eend = ebeg + btot[b];
  for (int p = ebeg + tid; p < eend; p += 256)
    atomicAdd(&cnt[binned[p] & 127], 1);
  __syncthreads();
  int v = (tid < 128) ? cnt[tid] : 0;
  if (tid < 128) sc[tid] = v;
  __syncthreads();
  for (int off = 1; off < 128; off <<= 1) {
    int tmp = (tid < 128 && tid >= off) ? sc[tid - off] : 0;
    __syncthreads();
    if (tid < 128) sc[tid] += tmp;
    __syncthreads();
  }
  if (tid < 128) {
    int ex = sc[tid] - v;
    rp[tid] = ebeg + ex;
    float dv = rsqrtf((float)v + 1.0f);
    sdv[tid] = dv;
    if (tid < nn) {
      rowptr[nb0 + tid] = ebeg + ex;
      deg[nb0 + tid] = v;
      dinv[nb0 + tid] = dv;
    }
    cnt[tid] = 0;
  }
  __syncthreads();
  for (int p = ebeg + tid; p < eend; p += 256) {
    unsigned pk = binned[p];
    int cl = pk & 127;
    int local = atomicAdd(&cnt[cl], 1);
    srcIdx[rp[cl] + local] = (int)(pk >> BSH);
  }
  // fused k_y: this bucket's x rows -> y = half(x*dinv)
  int tot = nn << 5;  // nn rows * 32 float4
  const float4* xb = x4 + ((size_t)nb0 << 5);
  float2* yb = y8 + ((size_t)nb0 << 5);
  for (int i = tid; i < tot; i += 256) {
    float sfac = sdv[i >> 5];
    float4 vv = xb[i];
    union { __half2 h[2]; float2 f; } u;
    u.h[0] = __floats2half2_rn(vv.x * sfac, vv.y * sfac);
    u.h[1] = __floats2half2_rn(vv.z * sfac, vv.w * sfac);
    yb[i] = u.f;
  }
}

// ---- fused gather + GEMM1(+bias,relu) + GEMM2(+dinv) ------------------------
// block = 16 rows, 4 waves, grid = NN/16 = 6250. Wave w gathers rows
// [w*4,w*4+4): whole wave on ONE node, 4 slots (quad) x 16-lane 256B chunks,
// up to 4 loads (4KB) in flight, butterfly combine. GEMM1: wave w -> col
// tiles 2w,2w+1. GEMM2: wave w -> col tile w. MFMA 16x16x32 f16, fp32 acc.
// (R5 dispatch-measured 90.0us, occ 72%, BW 2.3 TB/s.)
__global__ __launch_bounds__(256, 8) void k_fused(
    const __half* __restrict__ y, const int* __restrict__ rowptr,
    const int* __restrict__ deg, const int* __restrict__ srcIdx,
    const float* __restrict__ dinv, const __half* __restrict__ Wt1,
    const float* __restrict__ b1, const __half* __restrict__ Wt2,
    __half* __restrict__ z) {
  __shared__ __align__(16) __half sA[16][136];
  __shared__ __align__(16) __half sB[16][136];
  const int w = threadIdx.x >> 6, l = threadIdx.x & 63;
  const int blk0 = blockIdx.x * 16;
  const int quad = l >> 4, m = l & 15;

  for (int i = 0; i < 4; ++i) {
    const int lr = w * 4 + i;
    const int node = blk0 + lr;
    const int d = deg[node];
    const int ptr = rowptr[node];
    float acc[8];
#pragma unroll
    for (int j = 0; j < 8; j++) acc[j] = 0.0f;
    for (int base = 0; base < d; base += 64) {
      int cnt = min(64, d - base);
      int my = (l < cnt) ? srcIdx[ptr + base + l] : 0;
      int k = 0;
      for (; k + 16 <= cnt; k += 16) {     // 16 neighbors, 4 loads in flight
        int s0 = __shfl(my, k + quad);
        int s1 = __shfl(my, k + 4 + quad);
        int s2 = __shfl(my, k + 8 + quad);
        int s3 = __shfl(my, k + 12 + quad);
        f16x8 v0 = *reinterpret_cast<const f16x8*>(y + (size_t)s0 * 128 + m * 8);
        f16x8 v1 = *reinterpret_cast<const f16x8*>(y + (size_t)s1 * 128 + m * 8);
        f16x8 v2 = *reinterpret_cast<const f16x8*>(y + (size_t)s2 * 128 + m * 8);
        f16x8 v3 = *reinterpret_cast<const f16x8*>(y + (size_t)s3 * 128 + m * 8);
#pragma unroll
        for (int j = 0; j < 8; j++) acc[j] += (float)v0[j];
#pragma unroll
        for (int j = 0; j < 8; j++) acc[j] += (float)v1[j];
#pragma unroll
        for (int j = 0; j < 8; j++) acc[j] += (float)v2[j];
#pragma unroll
        for (int j = 0; j < 8; j++) acc[j] += (float)v3[j];
      }
      for (; k + 8 <= cnt; k += 8) {       // 8 neighbors, 2 loads in flight
        int s0 = __shfl(my, k + quad);
        int s1 = __shfl(my, k + 4 + quad);
        f16x8 v0 = *reinterpret_cast<const f16x8*>(y + (size_t)s0 * 128 + m * 8);
        f16x8 v1 = *reinterpret_cast<const f16x8*>(y + (size_t)s1 * 128 + m * 8);
#pragma unroll
        for (int j = 0; j < 8; j++) acc[j] += (float)v0[j];
#pragma unroll
        for (int j = 0; j < 8; j++) acc[j] += (float)v1[j];
      }
      for (; k < cnt; k += 4) {            // remainder, predicated
        int idx = k + quad;
        bool valid = idx < cnt;
        int s0 = __shfl(my, valid ? idx : 0);
        f16x8 v0 = *reinterpret_cast<const f16x8*>(y + (size_t)s0 * 128 + m * 8);
        if (valid) {
#pragma unroll
          for (int j = 0; j < 8; j++) acc[j] += (float)v0[j];
        }
      }
    }
#pragma unroll
    for (int j = 0; j < 8; j++) acc[j] += __shfl_xor(acc[j], 16);
#pragma unroll
    for (int j = 0; j < 8; j++) acc[j] += __shfl_xor(acc[j], 32);
    if (quad == 0) {
      f16x8 sv = *reinterpret_cast<const f16x8*>(y + (size_t)node * 128 + m * 8);
      float scn = dinv[node];
      f16x8 o;
#pragma unroll
      for (int j = 0; j < 8; j++)
        o[j] = (_Float16)((acc[j] + (float)sv[j]) * scn);
      *reinterpret_cast<f16x8*>(&sA[lr][m * 8]) = o;
    }
  }
  __syncthreads();

  // GEMM1: wave w -> col tiles 2w, 2w+1
  f16x8 afrag[4];
#pragma unroll
  for (int kk = 0; kk < 4; kk++)
    afrag[kk] = *reinterpret_cast<const f16x8*>(&sA[m][kk * 32 + quad * 8]);
  f32x4 acc1[2];
#pragma unroll
  for (int t = 0; t < 2; t++) {
    float bv = b1[(w * 2 + t) * 16 + m];
    acc1[t] = (f32x4){bv, bv, bv, bv};
  }
#pragma unroll
  for (int kk = 0; kk < 4; kk++) {
#pragma unroll
    for (int t = 0; t < 2; t++) {
      f16x8 b = *reinterpret_cast<const f16x8*>(
          Wt1 + (size_t)((w * 2 + t) * 16 + m) * 128 + kk * 32 + quad * 8);
      acc1[t] = __builtin_amdgcn_mfma_f32_16x16x32_f16(afrag[kk], b, acc1[t], 0, 0, 0);
    }
  }
#pragma unroll
  for (int t = 0; t < 2; t++)
#pragma unroll
    for (int i = 0; i < 4; i++)
      sB[quad * 4 + i][(w * 2 + t) * 16 + m] =
          __float2half(fmaxf(acc1[t][i], 0.0f));
  __syncthreads();

  // GEMM2: wave w -> col tile w
  f16x8 hfrag[4];
#pragma unroll
  for (int kk = 0; kk < 4; kk++)
    hfrag[kk] = *reinterpret_cast<const f16x8*>(&sB[m][kk * 32 + quad * 8]);
  f32x4 acc2 = (f32x4){0.f, 0.f, 0.f, 0.f};
#pragma unroll
  for (int kk = 0; kk < 4; kk++) {
    f16x8 b = *reinterpret_cast<const f16x8*>(
        Wt2 + (size_t)(w * 16 + m) * 128 + kk * 32 + quad * 8);
    acc2 = __builtin_amdgcn_mfma_f32_16x16x32_f16(hfrag[kk], b, acc2, 0, 0, 0);
  }
  float rs[4];
#pragma unroll
  for (int i = 0; i < 4; i++) rs[i] = dinv[blk0 + quad * 4 + i];
#pragma unroll
  for (int i = 0; i < 4; i++)
    sA[quad * 4 + i][w * 16 + m] = __float2half(acc2[i] * rs[i]);
  __syncthreads();

  if (threadIdx.x < 128) {
    int r = threadIdx.x >> 3, cc = threadIdx.x & 7;
    *reinterpret_cast<float4*>(z + (size_t)(blk0 + r) * 64 + cc * 8) =
        *reinterpret_cast<const float4*>(&sA[r][cc * 8]);
  }
}

// ---------------- gather-aggregate, width 64 half (wave per node) ------------
// 16B/lane: 8 lanes/row -> 8 rows per load instruction; now 4-deep = 32 rows
// (4KB) in flight. Butterfly xor 8/16/32.
__global__ __launch_bounds__(256) void k_gath2(const __half* __restrict__ z,
                                               const int* __restrict__ rowptr,
                                               const int* __restrict__ deg,
                                               const int* __restrict__ srcIdx,
                                               const float* __restrict__ dinv,
                                               const float* __restrict__ b2,
                                               float* __restrict__ out) {
  int node = blockIdx.x * 4 + (threadIdx.x >> 6);
  if (node >= NN) return;
  int lane = threadIdx.x & 63;
  int g = lane >> 3;
  int c = lane & 7;
  int d = deg[node];
  int p = rowptr[node];
  size_t coff = (size_t)c * 8;
  float acc[8];
#pragma unroll
  for (int i = 0; i < 8; i++) acc[i] = 0.0f;

  for (int base = 0; base < d; base += 64) {
    int cnt = min(64, d - base);
    int my = (lane < cnt) ? srcIdx[p + base + lane] : 0;
    int k = 0;
    for (; k + 32 <= cnt; k += 32) {         // 32 neighbors, 4 loads in flight
      int s0 = __shfl(my, k + g);
      int s1 = __shfl(my, k + 8 + g);
      int s2 = __shfl(my, k + 16 + g);
      int s3 = __shfl(my, k + 24 + g);
      f16x8 v0 = *reinterpret_cast<const f16x8*>(z + (size_t)s0 * 64 + coff);
      f16x8 v1 = *reinterpret_cast<const f16x8*>(z + (size_t)s1 * 64 + coff);
      f16x8 v2 = *reinterpret_cast<const f16x8*>(z + (size_t)s2 * 64 + coff);
      f16x8 v3 = *reinterpret_cast<const f16x8*>(z + (size_t)s3 * 64 + coff);
#pragma unroll
      for (int i = 0; i < 8; i++) acc[i] += (float)v0[i];
#pragma unroll
      for (int i = 0; i < 8; i++) acc[i] += (float)v1[i];
#pragma unroll
      for (int i = 0; i < 8; i++) acc[i] += (float)v2[i];
#pragma unroll
      for (int i = 0; i < 8; i++) acc[i] += (float)v3[i];
    }
    for (; k + 16 <= cnt; k += 16) {         // 16 neighbors, 2 loads in flight
      int s0 = __shfl(my, k + g);
      int s1 = __shfl(my, k + 8 + g);
      f16x8 v0 = *reinterpret_cast<const f16x8*>(z + (size_t)s0 * 64 + coff);
      f16x8 v1 = *reinterpret_cast<const f16x8*>(z + (size_t)s1 * 64 + coff);
#pragma unroll
      for (int i = 0; i < 8; i++) acc[i] += (float)v0[i];
#pragma unroll
      for (int i = 0; i < 8; i++) acc[i] += (float)v1[i];
    }
    for (; k < cnt; k += 8) {                // remainder, predicated
      int idx = k + g;
      bool valid = idx < cnt;
      int s0 = __shfl(my, valid ? idx : 0);
      f16x8 v0 = *reinterpret_cast<const f16x8*>(z + (size_t)s0 * 64 + coff);
      if (valid) {
#pragma unroll
        for (int i = 0; i < 8; i++) acc[i] += (float)v0[i];
      }
    }
  }
#pragma unroll
  for (int i = 0; i < 8; i++) acc[i] += __shfl_xor(acc[i], 8);
#pragma unroll
  for (int i = 0; i < 8; i++) acc[i] += __shfl_xor(acc[i], 16);
#pragma unroll
  for (int i = 0; i < 8; i++) acc[i] += __shfl_xor(acc[i], 32);
  if (g == 0) {
    f16x8 sv = *reinterpret_cast<const f16x8*>(z + (size_t)node * 64 + coff);
    float s = dinv[node];
    const float4* b4 = reinterpret_cast<const float4*>(b2);
    float4 bv0 = b4[2 * c], bv1 = b4[2 * c + 1];
    float4 o0, o1;
    o0.x = (acc[0] + (float)sv[0]) * s + bv0.x;
    o0.y = (acc[1] + (float)sv[1]) * s + bv0.y;
    o0.z = (acc[2] + (float)sv[2]) * s + bv0.z;
    o0.w = (acc[3] + (float)sv[3]) * s + bv0.w;
    o1.x = (acc[4] + (float)sv[4]) * s + bv1.x;
    o1.y = (acc[5] + (float)sv[5]) * s + bv1.y;
    o1.z = (acc[6] + (float)sv[6]) * s + bv1.z;
    o1.w = (acc[7] + (float)sv[7]) * s + bv1.w;
    float4* op = reinterpret_cast<float4*>(out + (size_t)node * 64 + coff);
    op[0] = o0;
    op[1] = o1;
  }
}

extern "C" void kernel_launch(void* const* d_in, const int* in_sizes, int n_in,
                              void* d_out, int out_size, void* d_ws, size_t ws_size,
                              hipStream_t stream) {
  const float* x  = (const float*)d_in[0];
  const int*   ei = (const int*)d_in[1];  // [2, NE] row-major
  const int* rows = ei;
  const int* cols = ei + NE;
  const float* W1 = (const float*)d_in[3];
  const float* b1 = (const float*)d_in[4];
  const float* W2 = (const float*)d_in[5];
  const float* b2 = (const float*)d_in[6];
  float* out = (float*)d_out;

  char* base = (char*)d_ws;
  constexpr size_t MB = 1 << 20;
  int*      deg       = (int*)(base + 0 * MB);
  int*      rowptr    = (int*)(base + 1 * MB);
  float*    dinv      = (float*)(base + 2 * MB);
  int*      btot      = (int*)(base + 3 * MB);
  int*      bucketBase= (int*)(base + 3 * MB + 16 * 1024);
  __half*   Wt1       = (__half*)(base + 3 * MB + 64 * 1024);
  __half*   Wt2       = (__half*)(base + 3 * MB + 128 * 1024);
  int*      table     = (int*)(base + 4 * MB);
  int*      startOff  = (int*)(base + 5 * MB);
  unsigned* binned    = (unsigned*)(base + 6 * MB);
  int*      srcIdx    = (int*)(base + 13 * MB);
  __half*   y         = (__half*)(base + 20 * MB);
  __half*   z         = (__half*)(base + 46 * MB);

  k_histwt<<<NBLK + 96, 256, 0, stream>>>(cols, table, W1, W2, Wt1, Wt2);
  k_scanT<<<NB, 256, 0, stream>>>(table, startOff, btot);
  k_scatB<<<NBLK, 256, 0, stream>>>(rows, cols, startOff, btot, bucketBase,
                                    binned);
  k_fillb<<<NB, 256, 0, stream>>>(binned, bucketBase, btot, rowptr, deg, dinv,
                                  srcIdx, (const float4*)x, (float2*)y);
  k_fused<<<NN / 16, 256, 0, stream>>>(y, rowptr, deg, srcIdx, dinv,
                                       Wt1, b1, Wt2, z);
  k_gath2<<<(NN + 3) / 4, 256, 0, stream>>>(z, rowptr, deg, srcIdx, dinv, b2, out);
}